// Round 1
// baseline (956.241 us; speedup 1.0000x reference)
//
#include <hip/hip_runtime.h>

#define NN 50000
#define NE 800000
#define NG 128

__device__ __forceinline__ float lrelu(float x){ return x > 0.f ? x : 0.2f*x; }

// ---------------- CSR build ----------------
__global__ void k_count(const int* __restrict__ dst, int* __restrict__ degi, int E){
    int e = blockIdx.x*blockDim.x + threadIdx.x;
    if (e < E) atomicAdd(&degi[dst[e]], 1);
}

__global__ void k_dinv(const int* __restrict__ degi, float* __restrict__ dinv, int n){
    int i = blockIdx.x*blockDim.x + threadIdx.x;
    if (i < n) dinv[i] = rsqrtf((float)(degi[i] + 1));   // +1 = self loop
}

// single-block exclusive scan over n ints (n=50000), 1024 threads
__global__ void k_scan(const int* __restrict__ deg, int* __restrict__ rowptr, int n){
    const int T = 1024;
    __shared__ int lds[T];
    int per = (n + T - 1) / T;
    int start = threadIdx.x * per;
    int end   = min(start + per, n);
    int s = 0;
    for (int i = start; i < end; i++) s += deg[i];
    lds[threadIdx.x] = s;
    __syncthreads();
    for (int off = 1; off < T; off <<= 1){
        int t = (threadIdx.x >= off) ? lds[threadIdx.x - off] : 0;
        __syncthreads();
        lds[threadIdx.x] += t;
        __syncthreads();
    }
    int run = lds[threadIdx.x] - s;           // exclusive prefix
    for (int i = start; i < end; i++){ rowptr[i] = run; run += deg[i]; }
    if (threadIdx.x == T-1) rowptr[n] = run;  // total (thread T-1 range empty or last)
}

__global__ void k_scatter(const int* __restrict__ src, const int* __restrict__ dst,
                          const int* __restrict__ rowptr, int* __restrict__ cursor,
                          int* __restrict__ csr_src, int E){
    int e = blockIdx.x*blockDim.x + threadIdx.x;
    if (e < E){
        int d = dst[e];
        int pos = rowptr[d] + atomicAdd(&cursor[d], 1);
        csr_src[pos] = src[e];
    }
}

// ---------------- small matmul: out[n][M] = in[n][0..K) @ W[K][M] ----------------
template<int K, int M>
__global__ void k_mm(const float* __restrict__ in, int istride,
                     const float* __restrict__ W, float* __restrict__ out, int n){
    __shared__ float wl[K*M];
    for (int i = threadIdx.x; i < K*M; i += blockDim.x) wl[i] = W[i];
    __syncthreads();
    constexpr int NPB = 256 / M;
    int m  = threadIdx.x % M;
    int nl = threadIdx.x / M;
    int node = blockIdx.x * NPB + nl;
    if (node >= n) return;
    const float* row = in + (size_t)node * istride;
    float acc = 0.f;
#pragma unroll 8
    for (int k = 0; k < K; k++) acc += row[k] * wl[k*M + m];
    out[(size_t)node*M + m] = acc;
}

// ---------------- mm4: [N,128] @ [128,256], 64x64 tiles ----------------
__global__ void k_mm4(const float* __restrict__ in, int istride,
                      const float* __restrict__ W, float* __restrict__ out, int n){
    __shared__ __align__(16) float xs[64][68];
    __shared__ __align__(16) float ws[64][68];
    int tid = threadIdx.x;
    int tx = tid & 15;   // output quad group
    int ty = tid >> 4;   // 0..15
    int nbase = blockIdx.y * 64;
    int cbase = blockIdx.x * 64;
    float acc[4][4] = {};
    for (int kb = 0; kb < 128; kb += 64){
#pragma unroll
        for (int p = 0; p < 4; p++){
            int r = p*16 + ty;
            int nn = nbase + r;
            float4 v = make_float4(0.f,0.f,0.f,0.f);
            if (nn < n) v = *(const float4*)(in + (size_t)nn*istride + kb + tx*4);
            *(float4*)&xs[r][tx*4] = v;
            float4 wv = *(const float4*)(W + (size_t)(kb + r)*256 + cbase + tx*4);
            *(float4*)&ws[r][tx*4] = wv;
        }
        __syncthreads();
#pragma unroll 16
        for (int k = 0; k < 64; k++){
            float4 wv = *(const float4*)&ws[k][tx*4];
#pragma unroll
            for (int i2 = 0; i2 < 4; i2++){
                float a = xs[ty*4 + i2][k];
                acc[i2][0] += a*wv.x; acc[i2][1] += a*wv.y;
                acc[i2][2] += a*wv.z; acc[i2][3] += a*wv.w;
            }
        }
        __syncthreads();
    }
#pragma unroll
    for (int i2 = 0; i2 < 4; i2++){
        int nn = nbase + ty*4 + i2;
        if (nn < n){
            float4 v = make_float4(acc[i2][0], acc[i2][1], acc[i2][2], acc[i2][3]);
            *(float4*)(out + (size_t)nn*256 + cbase + tx*4) = v;
        }
    }
}

// ---------------- GCN aggregation (gather over CSR) ----------------
template<int C>
__global__ void k_gcn_agg(const float* __restrict__ h, const float* __restrict__ dinv,
                          const int* __restrict__ rowptr, const int* __restrict__ csr_src,
                          const float* __restrict__ b, float* __restrict__ out,
                          int ostride, int n){
    constexpr int NPB = 256 / C;
    int c  = threadIdx.x % C;
    int nl = threadIdx.x / C;
    int i = blockIdx.x * NPB + nl;
    if (i >= n) return;
    float di = dinv[i];
    float ssum = di * h[(size_t)i*C + c];        // self loop: dinv[i]*h[i]
    int e0 = rowptr[i], e1 = rowptr[i+1];
    for (int e = e0; e < e1; e++){
        int j = csr_src[e];
        ssum += dinv[j] * h[(size_t)j*C + c];
    }
    out[(size_t)i*ostride + c] = fmaxf(di*ssum + b[c], 0.f);
}

// ---------------- GAT attention coefficients ----------------
template<int H, int C>
__global__ void k_att(const float* __restrict__ h, const float* __restrict__ att_s,
                      const float* __restrict__ att_d, float* __restrict__ asrc,
                      float* __restrict__ adst, int n){
    int idx = blockIdx.x*blockDim.x + threadIdx.x;
    int i = idx / H, hh = idx % H;
    if (i >= n) return;
    const float* row = h + (size_t)i*H*C + hh*C;
    float s = 0.f, d = 0.f;
#pragma unroll
    for (int c = 0; c < C; c++){
        float v = row[c];
        s += v * att_s[hh*C + c];
        d += v * att_d[hh*C + c];
    }
    asrc[(size_t)i*H + hh] = s;
    adst[(size_t)i*H + hh] = d;
}

// ---------------- GAT aggregation: one wave per dst node ----------------
// softmax shift-invariance: skip segment_max, compute exp(e)/sum directly
template<int H, int C>
__global__ void k_gat_agg(const float* __restrict__ h, const float* __restrict__ asrc,
                          const float* __restrict__ adst, const int* __restrict__ rowptr,
                          const int* __restrict__ csr_src, const float* __restrict__ b,
                          float* __restrict__ out, int ostride, int n){
    constexpr int HC = H*C;
    constexpr int V  = HC/64;     // 2 (H=4) or 4 (H=8) floats per lane
    int lane = threadIdx.x & 63;
    int wid  = threadIdx.x >> 6;
    int i = blockIdx.x*4 + wid;
    if (i >= n) return;
    int head = (lane*V)/C;
    float ad = adst[(size_t)i*H + head];
    float wself = expf(lrelu(asrc[(size_t)i*H + head] + ad));
    float acc[V];
    float s = wself;
    if constexpr (V == 4){
        float4 t = *((const float4*)(h + (size_t)i*HC) + lane);
        acc[0] = wself*t.x; acc[1] = wself*t.y; acc[2] = wself*t.z; acc[3] = wself*t.w;
    } else {
        float2 t = *((const float2*)(h + (size_t)i*HC) + lane);
        acc[0] = wself*t.x; acc[1] = wself*t.y;
    }
    int e0 = rowptr[i], e1 = rowptr[i+1];
    for (int e = e0; e < e1; e++){
        int j = csr_src[e];
        float w = expf(lrelu(asrc[(size_t)j*H + head] + ad));
        if constexpr (V == 4){
            float4 t = *((const float4*)(h + (size_t)j*HC) + lane);
            acc[0] += w*t.x; acc[1] += w*t.y; acc[2] += w*t.z; acc[3] += w*t.w;
        } else {
            float2 t = *((const float2*)(h + (size_t)j*HC) + lane);
            acc[0] += w*t.x; acc[1] += w*t.y;
        }
        s += w;
    }
    float inv = 1.f / s;
#pragma unroll
    for (int v = 0; v < V; v++)
        out[(size_t)i*ostride + lane*V + v] = fmaxf(acc[v]*inv + b[lane*V + v], 0.f);
}

// ---------------- pooling + FC ----------------
__global__ void k_bounds(const int* __restrict__ batch, int* __restrict__ gstart, int n, int G){
    int g = threadIdx.x;
    if (g > G) return;
    int lo = 0, hi = n;
    while (lo < hi){ int mid = (lo+hi) >> 1; if (batch[mid] < g) lo = mid+1; else hi = mid; }
    gstart[g] = lo;
}

__global__ void k_pool(const float* __restrict__ xj, const int* __restrict__ gstart,
                       float* __restrict__ pool){
    int g = blockIdx.x;
    int s = gstart[g], e = gstart[g+1];
    float invc = (e > s) ? 1.f/(float)(e - s) : 0.f;
    for (int c = threadIdx.x; c < 432; c += blockDim.x){
        float acc = 0.f;
        for (int nn = s; nn < e; nn++) acc += xj[(size_t)nn*432 + c];
        pool[g*432 + c] = acc * invc;
    }
}

__global__ void k_fc1(const float* __restrict__ pool, const float* __restrict__ W,
                      const float* __restrict__ b, float* __restrict__ hfc){
    int g = blockIdx.x, j = threadIdx.x;   // 128 threads
    float acc = 0.f;
    for (int k = 0; k < 432; k++) acc += pool[g*432 + k] * W[k*128 + j];
    hfc[g*128 + j] = fmaxf(acc + b[j], 0.f);
}

__global__ void k_fc2(const float* __restrict__ hfc, const float* __restrict__ W,
                      const float* __restrict__ b, float* __restrict__ out){
    int g = blockIdx.x, t = threadIdx.x;   // 128 threads
    float p = hfc[g*128 + t] * W[t];
    for (int off = 32; off > 0; off >>= 1) p += __shfl_down(p, off, 64);
    __shared__ float part[2];
    if ((t & 63) == 0) part[t >> 6] = p;
    __syncthreads();
    if (t == 0) out[g] = part[0] + part[1] + b[0];
}

extern "C" void kernel_launch(void* const* d_in, const int* in_sizes, int n_in,
                              void* d_out, int out_size, void* d_ws, size_t ws_size,
                              hipStream_t stream){
    const float* x     = (const float*)d_in[0];
    const int*   ei    = (const int*)  d_in[1];
    const int*   batch = (const int*)  d_in[2];
    const float* W1 = (const float*)d_in[3];  const float* b1 = (const float*)d_in[4];
    const float* W2 = (const float*)d_in[5];  const float* b2 = (const float*)d_in[6];
    const float* W3 = (const float*)d_in[7];
    const float* as3 = (const float*)d_in[8]; const float* ad3 = (const float*)d_in[9];
    const float* b3 = (const float*)d_in[10];
    const float* W4 = (const float*)d_in[11];
    const float* as4 = (const float*)d_in[12]; const float* ad4 = (const float*)d_in[13];
    const float* b4 = (const float*)d_in[14];
    const float* Wf1 = (const float*)d_in[15]; const float* bf1 = (const float*)d_in[16];
    const float* Wf2 = (const float*)d_in[17]; const float* bf2 = (const float*)d_in[18];
    float* out = (float*)d_out;

    const int* srcE = ei;
    const int* dstE = ei + NE;

    char* base = (char*)d_ws; size_t off = 0;
    auto alloc = [&](size_t bytes)->void*{
        void* p = base + off;
        off += (bytes + 255) & ~(size_t)255;
        return p;
    };
    int*   degi    = (int*)  alloc((size_t)NN*4);
    int*   cursor  = (int*)  alloc((size_t)NN*4);
    float* dinv    = (float*)alloc((size_t)NN*4);
    int*   rowptr  = (int*)  alloc((size_t)(NN+1)*4);
    int*   csr_src = (int*)  alloc((size_t)NE*4);
    float* h_buf   = (float*)alloc((size_t)NN*256*4);   // reused: h1,h2,h3,h4
    float* xj      = (float*)alloc((size_t)NN*432*4);   // jump concat [x1|x2|x3|x4]
    float* a_src   = (float*)alloc((size_t)NN*8*4);
    float* a_dst   = (float*)alloc((size_t)NN*8*4);
    int*   gstart  = (int*)  alloc((size_t)(NG+1)*4);
    float* pool    = (float*)alloc((size_t)NG*432*4);
    float* hfc     = (float*)alloc((size_t)NG*128*4);

    hipMemsetAsync(degi, 0, (size_t)NN*4, stream);
    hipMemsetAsync(cursor, 0, (size_t)NN*4, stream);

    const int EB = (NE + 255)/256;
    const int NB = (NN + 255)/256;

    k_count  <<<EB, 256, 0, stream>>>(dstE, degi, NE);
    k_dinv   <<<NB, 256, 0, stream>>>(degi, dinv, NN);
    k_scan   <<<1, 1024, 0, stream>>>(degi, rowptr, NN);
    k_scatter<<<EB, 256, 0, stream>>>(srcE, dstE, rowptr, cursor, csr_src, NE);

    // GCN layer 1: x[N,128] @ W1[128,16] -> agg -> relu -> xj[:,0:16]
    k_mm<128,16> <<<(NN+15)/16, 256, 0, stream>>>(x, 128, W1, h_buf, NN);
    k_gcn_agg<16><<<(NN+15)/16, 256, 0, stream>>>(h_buf, dinv, rowptr, csr_src, b1, xj + 0, 432, NN);

    // GCN layer 2: x1[N,16] @ W2[16,32] -> agg -> relu -> xj[:,16:48]
    k_mm<16,32>  <<<(NN+7)/8, 256, 0, stream>>>(xj + 0, 432, W2, h_buf, NN);
    k_gcn_agg<32><<<(NN+7)/8, 256, 0, stream>>>(h_buf, dinv, rowptr, csr_src, b2, xj + 16, 432, NN);

    // GAT layer 3: x2[N,32] @ W3[32,128] (4 heads x 32) -> xj[:,48:176]
    k_mm<32,128> <<<(NN+1)/2, 256, 0, stream>>>(xj + 16, 432, W3, h_buf, NN);
    k_att<4,32>  <<<(NN*4 + 255)/256, 256, 0, stream>>>(h_buf, as3, ad3, a_src, a_dst, NN);
    k_gat_agg<4,32><<<(NN+3)/4, 256, 0, stream>>>(h_buf, a_src, a_dst, rowptr, csr_src, b3, xj + 48, 432, NN);

    // GAT layer 4: x3[N,128] @ W4[128,256] (8 heads x 32) -> xj[:,176:432]
    {
        dim3 grid(4, (NN + 63)/64);
        k_mm4<<<grid, 256, 0, stream>>>(xj + 48, 432, W4, h_buf, NN);
    }
    k_att<8,32>  <<<(NN*8 + 255)/256, 256, 0, stream>>>(h_buf, as4, ad4, a_src, a_dst, NN);
    k_gat_agg<8,32><<<(NN+3)/4, 256, 0, stream>>>(h_buf, a_src, a_dst, rowptr, csr_src, b4, xj + 176, 432, NN);

    // pooling + FC
    k_bounds<<<1, 256, 0, stream>>>(batch, gstart, NN, NG);
    k_pool  <<<NG, 256, 0, stream>>>(xj, gstart, pool);
    k_fc1   <<<NG, 128, 0, stream>>>(pool, Wf1, bf1, hfc);
    k_fc2   <<<NG, 128, 0, stream>>>(hfc, Wf2, bf2, out);
}

// Round 2
// 763.402 us; speedup vs baseline: 1.2526x; 1.2526x over previous
//
#include <hip/hip_runtime.h>

#define NN 50000
#define NE 800000
#define NG 128

__device__ __forceinline__ float lrelu(float x){ return x > 0.f ? x : 0.2f*x; }

// ---------------- CSR build ----------------
__global__ void k_count(const int* __restrict__ dst, int* __restrict__ degi, int E){
    int e = blockIdx.x*blockDim.x + threadIdx.x;
    if (e < E) atomicAdd(&degi[dst[e]], 1);
}

__global__ void k_dinv(const int* __restrict__ degi, float* __restrict__ dinv, int n){
    int i = blockIdx.x*blockDim.x + threadIdx.x;
    if (i < n) dinv[i] = rsqrtf((float)(degi[i] + 1));   // +1 = self loop
}

// single-block exclusive scan over n ints (n=50000), 1024 threads
__global__ void k_scan(const int* __restrict__ deg, int* __restrict__ rowptr, int n){
    const int T = 1024;
    __shared__ int lds[T];
    int per = (n + T - 1) / T;
    int start = threadIdx.x * per;
    int end   = min(start + per, n);
    int s = 0;
    for (int i = start; i < end; i++) s += deg[i];
    lds[threadIdx.x] = s;
    __syncthreads();
    for (int off = 1; off < T; off <<= 1){
        int t = (threadIdx.x >= off) ? lds[threadIdx.x - off] : 0;
        __syncthreads();
        lds[threadIdx.x] += t;
        __syncthreads();
    }
    int run = lds[threadIdx.x] - s;           // exclusive prefix
    for (int i = start; i < end; i++){ rowptr[i] = run; run += deg[i]; }
    if (threadIdx.x == T-1) rowptr[n] = run;  // total (thread T-1 range empty or last)
}

__global__ void k_scatter(const int* __restrict__ src, const int* __restrict__ dst,
                          const int* __restrict__ rowptr, int* __restrict__ cursor,
                          int* __restrict__ csr_src, int E){
    int e = blockIdx.x*blockDim.x + threadIdx.x;
    if (e < E){
        int d = dst[e];
        int pos = rowptr[d] + atomicAdd(&cursor[d], 1);
        csr_src[pos] = src[e];
    }
}

// ---------------- small matmul: out[n][M] = in[n][0..K) @ W[K][M] ----------------
template<int K, int M>
__global__ void k_mm(const float* __restrict__ in, int istride,
                     const float* __restrict__ W, float* __restrict__ out, int n){
    __shared__ float wl[K*M];
    for (int i = threadIdx.x; i < K*M; i += blockDim.x) wl[i] = W[i];
    __syncthreads();
    constexpr int NPB = 256 / M;
    int m  = threadIdx.x % M;
    int nl = threadIdx.x / M;
    int node = blockIdx.x * NPB + nl;
    if (node >= n) return;
    const float* row = in + (size_t)node * istride;
    float acc = 0.f;
#pragma unroll 8
    for (int k = 0; k < K; k++) acc += row[k] * wl[k*M + m];
    out[(size_t)node*M + m] = acc;
}

// ---------------- mm4: [N,128] @ [128,256], 64x64 tiles ----------------
__global__ void k_mm4(const float* __restrict__ in, int istride,
                      const float* __restrict__ W, float* __restrict__ out, int n){
    __shared__ __align__(16) float xs[64][68];
    __shared__ __align__(16) float ws[64][68];
    int tid = threadIdx.x;
    int tx = tid & 15;   // output quad group
    int ty = tid >> 4;   // 0..15
    int nbase = blockIdx.y * 64;
    int cbase = blockIdx.x * 64;
    float acc[4][4] = {};
    for (int kb = 0; kb < 128; kb += 64){
#pragma unroll
        for (int p = 0; p < 4; p++){
            int r = p*16 + ty;
            int nn = nbase + r;
            float4 v = make_float4(0.f,0.f,0.f,0.f);
            if (nn < n) v = *(const float4*)(in + (size_t)nn*istride + kb + tx*4);
            *(float4*)&xs[r][tx*4] = v;
            float4 wv = *(const float4*)(W + (size_t)(kb + r)*256 + cbase + tx*4);
            *(float4*)&ws[r][tx*4] = wv;
        }
        __syncthreads();
#pragma unroll 16
        for (int k = 0; k < 64; k++){
            float4 wv = *(const float4*)&ws[k][tx*4];
#pragma unroll
            for (int i2 = 0; i2 < 4; i2++){
                float a = xs[ty*4 + i2][k];
                acc[i2][0] += a*wv.x; acc[i2][1] += a*wv.y;
                acc[i2][2] += a*wv.z; acc[i2][3] += a*wv.w;
            }
        }
        __syncthreads();
    }
#pragma unroll
    for (int i2 = 0; i2 < 4; i2++){
        int nn = nbase + ty*4 + i2;
        if (nn < n){
            float4 v = make_float4(acc[i2][0], acc[i2][1], acc[i2][2], acc[i2][3]);
            *(float4*)(out + (size_t)nn*256 + cbase + tx*4) = v;
        }
    }
}

// ---------------- GCN aggregation (gather over CSR) ----------------
template<int C>
__global__ void k_gcn_agg(const float* __restrict__ h, const float* __restrict__ dinv,
                          const int* __restrict__ rowptr, const int* __restrict__ csr_src,
                          const float* __restrict__ b, float* __restrict__ out,
                          int ostride, int n){
    constexpr int NPB = 256 / C;
    int c  = threadIdx.x % C;
    int nl = threadIdx.x / C;
    int i = blockIdx.x * NPB + nl;
    if (i >= n) return;
    float di = dinv[i];
    float ssum = di * h[(size_t)i*C + c];        // self loop: dinv[i]*h[i]
    int e0 = rowptr[i], e1 = rowptr[i+1];
    for (int e = e0; e < e1; e++){
        int j = csr_src[e];
        ssum += dinv[j] * h[(size_t)j*C + c];
    }
    out[(size_t)i*ostride + c] = fmaxf(di*ssum + b[c], 0.f);
}

// ---------------- GAT attention coefficients ----------------
template<int H, int C>
__global__ void k_att(const float* __restrict__ h, const float* __restrict__ att_s,
                      const float* __restrict__ att_d, float* __restrict__ asrc,
                      float* __restrict__ adst, int n){
    int idx = blockIdx.x*blockDim.x + threadIdx.x;
    int i = idx / H, hh = idx % H;
    if (i >= n) return;
    const float* row = h + (size_t)i*H*C + hh*C;
    float s = 0.f, d = 0.f;
#pragma unroll
    for (int c = 0; c < C; c++){
        float v = row[c];
        s += v * att_s[hh*C + c];
        d += v * att_d[hh*C + c];
    }
    asrc[(size_t)i*H + hh] = s;
    adst[(size_t)i*H + hh] = d;
}

// ---------------- GAT aggregation: one wave per dst node ----------------
// softmax shift-invariance: skip segment_max, compute exp(e)/sum directly
template<int H, int C>
__global__ void k_gat_agg(const float* __restrict__ h, const float* __restrict__ asrc,
                          const float* __restrict__ adst, const int* __restrict__ rowptr,
                          const int* __restrict__ csr_src, const float* __restrict__ b,
                          float* __restrict__ out, int ostride, int n){
    constexpr int HC = H*C;
    constexpr int V  = HC/64;     // 2 (H=4) or 4 (H=8) floats per lane
    int lane = threadIdx.x & 63;
    int wid  = threadIdx.x >> 6;
    int i = blockIdx.x*4 + wid;
    if (i >= n) return;
    int head = (lane*V)/C;
    float ad = adst[(size_t)i*H + head];
    float wself = expf(lrelu(asrc[(size_t)i*H + head] + ad));
    float acc[V];
    float s = wself;
    if constexpr (V == 4){
        float4 t = *((const float4*)(h + (size_t)i*HC) + lane);
        acc[0] = wself*t.x; acc[1] = wself*t.y; acc[2] = wself*t.z; acc[3] = wself*t.w;
    } else {
        float2 t = *((const float2*)(h + (size_t)i*HC) + lane);
        acc[0] = wself*t.x; acc[1] = wself*t.y;
    }
    int e0 = rowptr[i], e1 = rowptr[i+1];
    for (int e = e0; e < e1; e++){
        int j = csr_src[e];
        float w = expf(lrelu(asrc[(size_t)j*H + head] + ad));
        if constexpr (V == 4){
            float4 t = *((const float4*)(h + (size_t)j*HC) + lane);
            acc[0] += w*t.x; acc[1] += w*t.y; acc[2] += w*t.z; acc[3] += w*t.w;
        } else {
            float2 t = *((const float2*)(h + (size_t)j*HC) + lane);
            acc[0] += w*t.x; acc[1] += w*t.y;
        }
        s += w;
    }
    float inv = 1.f / s;
#pragma unroll
    for (int v = 0; v < V; v++)
        out[(size_t)i*ostride + lane*V + v] = fmaxf(acc[v]*inv + b[lane*V + v], 0.f);
}

// ---------------- pooling + FC ----------------
__global__ void k_bounds(const int* __restrict__ batch, int* __restrict__ gstart, int n, int G){
    int g = threadIdx.x;
    if (g > G) return;
    int lo = 0, hi = n;
    while (lo < hi){ int mid = (lo+hi) >> 1; if (batch[mid] < g) lo = mid+1; else hi = mid; }
    gstart[g] = lo;
}

// node-parallel pooling: each block owns 32 consecutive nodes (batch sorted),
// register-accumulate per channel until graph id changes, then flush atomics.
__global__ void k_pool_sum(const float* __restrict__ xj, const int* __restrict__ batch,
                           float* __restrict__ pool){
    int nb = blockIdx.x * 32;
    int ne = min(nb + 32, NN);
    if (nb >= NN) return;
    int c0 = threadIdx.x;          // < 432 always (256 threads)
    int c1 = threadIdx.x + 256;    // valid if < 432
    float a0 = 0.f, a1 = 0.f;
    int curg = batch[nb];
    for (int nn = nb; nn < ne; nn++){
        int g = batch[nn];                       // block-uniform (scalar load)
        if (g != curg){
            atomicAdd(&pool[curg*432 + c0], a0);
            if (c1 < 432) atomicAdd(&pool[curg*432 + c1], a1);
            a0 = 0.f; a1 = 0.f; curg = g;
        }
        a0 += xj[(size_t)nn*432 + c0];
        if (c1 < 432) a1 += xj[(size_t)nn*432 + c1];
    }
    atomicAdd(&pool[curg*432 + c0], a0);
    if (c1 < 432) atomicAdd(&pool[curg*432 + c1], a1);
}

__global__ void k_fc1(const float* __restrict__ pool, const int* __restrict__ gstart,
                      const float* __restrict__ W, const float* __restrict__ b,
                      float* __restrict__ hfc){
    int g = blockIdx.x, j = threadIdx.x;   // 128 threads
    int cnt = gstart[g+1] - gstart[g];
    float invc = 1.f / (float)max(cnt, 1);
    float acc = 0.f;
    for (int k = 0; k < 432; k++) acc += pool[g*432 + k] * W[k*128 + j];
    hfc[g*128 + j] = fmaxf(acc * invc + b[j], 0.f);
}

__global__ void k_fc2(const float* __restrict__ hfc, const float* __restrict__ W,
                      const float* __restrict__ b, float* __restrict__ out){
    int g = blockIdx.x, t = threadIdx.x;   // 128 threads
    float p = hfc[g*128 + t] * W[t];
    for (int off = 32; off > 0; off >>= 1) p += __shfl_down(p, off, 64);
    __shared__ float part[2];
    if ((t & 63) == 0) part[t >> 6] = p;
    __syncthreads();
    if (t == 0) out[g] = part[0] + part[1] + b[0];
}

extern "C" void kernel_launch(void* const* d_in, const int* in_sizes, int n_in,
                              void* d_out, int out_size, void* d_ws, size_t ws_size,
                              hipStream_t stream){
    const float* x     = (const float*)d_in[0];
    const int*   ei    = (const int*)  d_in[1];
    const int*   batch = (const int*)  d_in[2];
    const float* W1 = (const float*)d_in[3];  const float* b1 = (const float*)d_in[4];
    const float* W2 = (const float*)d_in[5];  const float* b2 = (const float*)d_in[6];
    const float* W3 = (const float*)d_in[7];
    const float* as3 = (const float*)d_in[8]; const float* ad3 = (const float*)d_in[9];
    const float* b3 = (const float*)d_in[10];
    const float* W4 = (const float*)d_in[11];
    const float* as4 = (const float*)d_in[12]; const float* ad4 = (const float*)d_in[13];
    const float* b4 = (const float*)d_in[14];
    const float* Wf1 = (const float*)d_in[15]; const float* bf1 = (const float*)d_in[16];
    const float* Wf2 = (const float*)d_in[17]; const float* bf2 = (const float*)d_in[18];
    float* out = (float*)d_out;

    const int* srcE = ei;
    const int* dstE = ei + NE;

    char* base = (char*)d_ws; size_t off = 0;
    auto alloc = [&](size_t bytes)->void*{
        void* p = base + off;
        off += (bytes + 255) & ~(size_t)255;
        return p;
    };
    int*   degi    = (int*)  alloc((size_t)NN*4);
    int*   cursor  = (int*)  alloc((size_t)NN*4);
    float* dinv    = (float*)alloc((size_t)NN*4);
    int*   rowptr  = (int*)  alloc((size_t)(NN+1)*4);
    int*   csr_src = (int*)  alloc((size_t)NE*4);
    float* h_buf   = (float*)alloc((size_t)NN*256*4);   // reused: h1,h2,h3,h4
    float* xj      = (float*)alloc((size_t)NN*432*4);   // jump concat [x1|x2|x3|x4]
    float* a_src   = (float*)alloc((size_t)NN*8*4);
    float* a_dst   = (float*)alloc((size_t)NN*8*4);
    int*   gstart  = (int*)  alloc((size_t)(NG+1)*4);
    float* pool    = (float*)alloc((size_t)NG*432*4);
    float* hfc     = (float*)alloc((size_t)NG*128*4);

    hipMemsetAsync(degi, 0, (size_t)NN*4, stream);
    hipMemsetAsync(cursor, 0, (size_t)NN*4, stream);
    hipMemsetAsync(pool, 0, (size_t)NG*432*4, stream);

    const int EB = (NE + 255)/256;
    const int NB = (NN + 255)/256;

    k_count  <<<EB, 256, 0, stream>>>(dstE, degi, NE);
    k_dinv   <<<NB, 256, 0, stream>>>(degi, dinv, NN);
    k_scan   <<<1, 1024, 0, stream>>>(degi, rowptr, NN);
    k_scatter<<<EB, 256, 0, stream>>>(srcE, dstE, rowptr, cursor, csr_src, NE);

    // GCN layer 1: x[N,128] @ W1[128,16] -> agg -> relu -> xj[:,0:16]
    k_mm<128,16> <<<(NN+15)/16, 256, 0, stream>>>(x, 128, W1, h_buf, NN);
    k_gcn_agg<16><<<(NN+15)/16, 256, 0, stream>>>(h_buf, dinv, rowptr, csr_src, b1, xj + 0, 432, NN);

    // GCN layer 2: x1[N,16] @ W2[16,32] -> agg -> relu -> xj[:,16:48]
    k_mm<16,32>  <<<(NN+7)/8, 256, 0, stream>>>(xj + 0, 432, W2, h_buf, NN);
    k_gcn_agg<32><<<(NN+7)/8, 256, 0, stream>>>(h_buf, dinv, rowptr, csr_src, b2, xj + 16, 432, NN);

    // GAT layer 3: x2[N,32] @ W3[32,128] (4 heads x 32) -> xj[:,48:176]
    k_mm<32,128> <<<(NN+1)/2, 256, 0, stream>>>(xj + 16, 432, W3, h_buf, NN);
    k_att<4,32>  <<<(NN*4 + 255)/256, 256, 0, stream>>>(h_buf, as3, ad3, a_src, a_dst, NN);
    k_gat_agg<4,32><<<(NN+3)/4, 256, 0, stream>>>(h_buf, a_src, a_dst, rowptr, csr_src, b3, xj + 48, 432, NN);

    // GAT layer 4: x3[N,128] @ W4[128,256] (8 heads x 32) -> xj[:,176:432]
    {
        dim3 grid(4, (NN + 63)/64);
        k_mm4<<<grid, 256, 0, stream>>>(xj + 48, 432, W4, h_buf, NN);
    }
    k_att<8,32>  <<<(NN*8 + 255)/256, 256, 0, stream>>>(h_buf, as4, ad4, a_src, a_dst, NN);
    k_gat_agg<8,32><<<(NN+3)/4, 256, 0, stream>>>(h_buf, a_src, a_dst, rowptr, csr_src, b4, xj + 176, 432, NN);

    // pooling + FC
    k_bounds<<<1, 256, 0, stream>>>(batch, gstart, NN, NG);
    k_pool_sum<<<(NN+31)/32, 256, 0, stream>>>(xj, batch, pool);
    k_fc1   <<<NG, 128, 0, stream>>>(pool, gstart, Wf1, bf1, hfc);
    k_fc2   <<<NG, 128, 0, stream>>>(hfc, Wf2, bf2, out);
}

// Round 3
// 727.047 us; speedup vs baseline: 1.3152x; 1.0500x over previous
//
#include <hip/hip_runtime.h>
#include <hip/hip_bf16.h>

#define NN 50000
#define NE 800000
#define NG 128

typedef unsigned short u16;

__device__ __forceinline__ float lrelu(float x){ return x > 0.f ? x : 0.2f*x; }
__device__ __forceinline__ float bf2f(u16 u){ return __uint_as_float(((unsigned int)u) << 16); }
__device__ __forceinline__ u16 f2bf(float f){
    __hip_bfloat16 h = __float2bfloat16(f);
    return *(u16*)&h;
}

// ---------------- CSR build ----------------
__global__ void k_count(const int* __restrict__ dst, int* __restrict__ degi, int E){
    int e = blockIdx.x*blockDim.x + threadIdx.x;
    if (e < E) atomicAdd(&degi[dst[e]], 1);
}

__global__ void k_dinv(const int* __restrict__ degi, float* __restrict__ dinv, int n){
    int i = blockIdx.x*blockDim.x + threadIdx.x;
    if (i < n) dinv[i] = rsqrtf((float)(degi[i] + 1));   // +1 = self loop
}

// single-block exclusive scan over n ints (n=50000), 1024 threads
__global__ void k_scan(const int* __restrict__ deg, int* __restrict__ rowptr, int n){
    const int T = 1024;
    __shared__ int lds[T];
    int per = (n + T - 1) / T;
    int start = threadIdx.x * per;
    int end   = min(start + per, n);
    int s = 0;
    for (int i = start; i < end; i++) s += deg[i];
    lds[threadIdx.x] = s;
    __syncthreads();
    for (int off = 1; off < T; off <<= 1){
        int t = (threadIdx.x >= off) ? lds[threadIdx.x - off] : 0;
        __syncthreads();
        lds[threadIdx.x] += t;
        __syncthreads();
    }
    int run = lds[threadIdx.x] - s;           // exclusive prefix
    for (int i = start; i < end; i++){ rowptr[i] = run; run += deg[i]; }
    if (threadIdx.x == T-1) rowptr[n] = run;
}

__global__ void k_scatter(const int* __restrict__ src, const int* __restrict__ dst,
                          const int* __restrict__ rowptr, int* __restrict__ cursor,
                          int* __restrict__ csr_src, int E){
    int e = blockIdx.x*blockDim.x + threadIdx.x;
    if (e < E){
        int d = dst[e];
        int pos = rowptr[d] + atomicAdd(&cursor[d], 1);
        csr_src[pos] = src[e];
    }
}

// ---------------- small matmul (fp32 out): out[n][M] = in[n][0..K) @ W[K][M] ----------------
template<int K, int M>
__global__ void k_mm(const float* __restrict__ in, int istride,
                     const float* __restrict__ W, float* __restrict__ out, int n){
    __shared__ float wl[K*M];
    for (int i = threadIdx.x; i < K*M; i += blockDim.x) wl[i] = W[i];
    __syncthreads();
    constexpr int NPB = 256 / M;
    int m  = threadIdx.x % M;
    int nl = threadIdx.x / M;
    int node = blockIdx.x * NPB + nl;
    if (node >= n) return;
    const float* row = in + (size_t)node * istride;
    float acc = 0.f;
#pragma unroll 8
    for (int k = 0; k < K; k++) acc += row[k] * wl[k*M + m];
    out[(size_t)node*M + m] = acc;
}

// bf16-out variant (for GAT h matrices)
template<int K, int M>
__global__ void k_mm_bf(const float* __restrict__ in, int istride,
                        const float* __restrict__ W, u16* __restrict__ out, int n){
    __shared__ float wl[K*M];
    for (int i = threadIdx.x; i < K*M; i += blockDim.x) wl[i] = W[i];
    __syncthreads();
    constexpr int NPB = 256 / M;
    int m  = threadIdx.x % M;
    int nl = threadIdx.x / M;
    int node = blockIdx.x * NPB + nl;
    if (node >= n) return;
    const float* row = in + (size_t)node * istride;
    float acc = 0.f;
#pragma unroll 8
    for (int k = 0; k < K; k++) acc += row[k] * wl[k*M + m];
    out[(size_t)node*M + m] = f2bf(acc);
}

// ---------------- mm4: [N,128] @ [128,256] -> bf16, 64x64 tiles ----------------
__global__ void k_mm4(const float* __restrict__ in, int istride,
                      const float* __restrict__ W, u16* __restrict__ out, int n){
    __shared__ __align__(16) float xs[64][68];
    __shared__ __align__(16) float ws[64][68];
    int tid = threadIdx.x;
    int tx = tid & 15;
    int ty = tid >> 4;
    int nbase = blockIdx.y * 64;
    int cbase = blockIdx.x * 64;
    float acc[4][4] = {};
    for (int kb = 0; kb < 128; kb += 64){
#pragma unroll
        for (int p = 0; p < 4; p++){
            int r = p*16 + ty;
            int nn = nbase + r;
            float4 v = make_float4(0.f,0.f,0.f,0.f);
            if (nn < n) v = *(const float4*)(in + (size_t)nn*istride + kb + tx*4);
            *(float4*)&xs[r][tx*4] = v;
            float4 wv = *(const float4*)(W + (size_t)(kb + r)*256 + cbase + tx*4);
            *(float4*)&ws[r][tx*4] = wv;
        }
        __syncthreads();
#pragma unroll 16
        for (int k = 0; k < 64; k++){
            float4 wv = *(const float4*)&ws[k][tx*4];
#pragma unroll
            for (int i2 = 0; i2 < 4; i2++){
                float a = xs[ty*4 + i2][k];
                acc[i2][0] += a*wv.x; acc[i2][1] += a*wv.y;
                acc[i2][2] += a*wv.z; acc[i2][3] += a*wv.w;
            }
        }
        __syncthreads();
    }
#pragma unroll
    for (int i2 = 0; i2 < 4; i2++){
        int nn = nbase + ty*4 + i2;
        if (nn < n){
            ushort4 v;
            v.x = f2bf(acc[i2][0]); v.y = f2bf(acc[i2][1]);
            v.z = f2bf(acc[i2][2]); v.w = f2bf(acc[i2][3]);
            *(ushort4*)(out + (size_t)nn*256 + cbase + tx*4) = v;
        }
    }
}

// ---------------- GCN aggregation (gather over CSR) ----------------
template<int C>
__global__ void k_gcn_agg(const float* __restrict__ h, const float* __restrict__ dinv,
                          const int* __restrict__ rowptr, const int* __restrict__ csr_src,
                          const float* __restrict__ b, float* __restrict__ out,
                          int ostride, int n){
    constexpr int NPB = 256 / C;
    int c  = threadIdx.x % C;
    int nl = threadIdx.x / C;
    int i = blockIdx.x * NPB + nl;
    if (i >= n) return;
    float di = dinv[i];
    float ssum = di * h[(size_t)i*C + c];        // self loop
    int e0 = rowptr[i], e1 = rowptr[i+1];
    for (int e = e0; e < e1; e++){
        int j = csr_src[e];
        ssum += dinv[j] * h[(size_t)j*C + c];
    }
    out[(size_t)i*ostride + c] = fmaxf(di*ssum + b[c], 0.f);
}

// ---------------- GAT attention coefficients (bf16 h) ----------------
template<int H, int C>
__global__ void k_att(const u16* __restrict__ h, const float* __restrict__ att_s,
                      const float* __restrict__ att_d, float* __restrict__ asrc,
                      float* __restrict__ adst, int n){
    int idx = blockIdx.x*blockDim.x + threadIdx.x;
    int i = idx / H, hh = idx % H;
    if (i >= n) return;
    const u16* row = h + (size_t)i*H*C + hh*C;
    float s = 0.f, d = 0.f;
#pragma unroll
    for (int c = 0; c < C; c++){
        float v = bf2f(row[c]);
        s += v * att_s[hh*C + c];
        d += v * att_d[hh*C + c];
    }
    asrc[(size_t)i*H + hh] = s;
    adst[(size_t)i*H + hh] = d;
}

// ---------------- GAT aggregation: one wave per dst node, bf16 h gather ----------------
template<int H, int C>
__global__ void k_gat_agg(const u16* __restrict__ h, const float* __restrict__ asrc,
                          const float* __restrict__ adst, const int* __restrict__ rowptr,
                          const int* __restrict__ csr_src, const float* __restrict__ b,
                          float* __restrict__ out, int ostride, int n){
    constexpr int HC = H*C;
    constexpr int V  = HC/64;     // 2 (H=4) or 4 (H=8) bf16 per lane
    int lane = threadIdx.x & 63;
    int wid  = threadIdx.x >> 6;
    int i = blockIdx.x*4 + wid;
    if (i >= n) return;
    int head = (lane*V)/C;
    float ad = adst[(size_t)i*H + head];
    float wself = expf(lrelu(asrc[(size_t)i*H + head] + ad));
    float acc[V];
    float s = wself;
    if constexpr (V == 4){
        ushort4 t = ((const ushort4*)(h + (size_t)i*HC))[lane];
        acc[0] = wself*bf2f(t.x); acc[1] = wself*bf2f(t.y);
        acc[2] = wself*bf2f(t.z); acc[3] = wself*bf2f(t.w);
    } else {
        ushort2 t = ((const ushort2*)(h + (size_t)i*HC))[lane];
        acc[0] = wself*bf2f(t.x); acc[1] = wself*bf2f(t.y);
    }
    int e0 = rowptr[i], e1 = rowptr[i+1];
    for (int e = e0; e < e1; e++){
        int j = csr_src[e];
        float w = expf(lrelu(asrc[(size_t)j*H + head] + ad));
        if constexpr (V == 4){
            ushort4 t = ((const ushort4*)(h + (size_t)j*HC))[lane];
            acc[0] += w*bf2f(t.x); acc[1] += w*bf2f(t.y);
            acc[2] += w*bf2f(t.z); acc[3] += w*bf2f(t.w);
        } else {
            ushort2 t = ((const ushort2*)(h + (size_t)j*HC))[lane];
            acc[0] += w*bf2f(t.x); acc[1] += w*bf2f(t.y);
        }
        s += w;
    }
    float inv = 1.f / s;
#pragma unroll
    for (int v = 0; v < V; v++)
        out[(size_t)i*ostride + lane*V + v] = fmaxf(acc[v]*inv + b[lane*V + v], 0.f);
}

// ---------------- pooling + FC ----------------
__global__ void k_bounds(const int* __restrict__ batch, int* __restrict__ gstart, int n, int G){
    int g = threadIdx.x;
    if (g > G) return;
    int lo = 0, hi = n;
    while (lo < hi){ int mid = (lo+hi) >> 1; if (batch[mid] < g) lo = mid+1; else hi = mid; }
    gstart[g] = lo;
}

__global__ void k_pool_sum(const float* __restrict__ xj, const int* __restrict__ batch,
                           float* __restrict__ pool){
    int nb = blockIdx.x * 32;
    int ne = min(nb + 32, NN);
    if (nb >= NN) return;
    int c0 = threadIdx.x;
    int c1 = threadIdx.x + 256;
    float a0 = 0.f, a1 = 0.f;
    int curg = batch[nb];
    for (int nn = nb; nn < ne; nn++){
        int g = batch[nn];
        if (g != curg){
            atomicAdd(&pool[curg*432 + c0], a0);
            if (c1 < 432) atomicAdd(&pool[curg*432 + c1], a1);
            a0 = 0.f; a1 = 0.f; curg = g;
        }
        a0 += xj[(size_t)nn*432 + c0];
        if (c1 < 432) a1 += xj[(size_t)nn*432 + c1];
    }
    atomicAdd(&pool[curg*432 + c0], a0);
    if (c1 < 432) atomicAdd(&pool[curg*432 + c1], a1);
}

__global__ void k_fc1(const float* __restrict__ pool, const int* __restrict__ gstart,
                      const float* __restrict__ W, const float* __restrict__ b,
                      float* __restrict__ hfc){
    int g = blockIdx.x, j = threadIdx.x;   // 128 threads
    int cnt = gstart[g+1] - gstart[g];
    float invc = 1.f / (float)max(cnt, 1);
    float acc = 0.f;
    for (int k = 0; k < 432; k++) acc += pool[g*432 + k] * W[k*128 + j];
    hfc[g*128 + j] = fmaxf(acc * invc + b[j], 0.f);
}

__global__ void k_fc2(const float* __restrict__ hfc, const float* __restrict__ W,
                      const float* __restrict__ b, float* __restrict__ out){
    int g = blockIdx.x, t = threadIdx.x;   // 128 threads
    float p = hfc[g*128 + t] * W[t];
    for (int off = 32; off > 0; off >>= 1) p += __shfl_down(p, off, 64);
    __shared__ float part[2];
    if ((t & 63) == 0) part[t >> 6] = p;
    __syncthreads();
    if (t == 0) out[g] = part[0] + part[1] + b[0];
}

extern "C" void kernel_launch(void* const* d_in, const int* in_sizes, int n_in,
                              void* d_out, int out_size, void* d_ws, size_t ws_size,
                              hipStream_t stream){
    const float* x     = (const float*)d_in[0];
    const int*   ei    = (const int*)  d_in[1];
    const int*   batch = (const int*)  d_in[2];
    const float* W1 = (const float*)d_in[3];  const float* b1 = (const float*)d_in[4];
    const float* W2 = (const float*)d_in[5];  const float* b2 = (const float*)d_in[6];
    const float* W3 = (const float*)d_in[7];
    const float* as3 = (const float*)d_in[8]; const float* ad3 = (const float*)d_in[9];
    const float* b3 = (const float*)d_in[10];
    const float* W4 = (const float*)d_in[11];
    const float* as4 = (const float*)d_in[12]; const float* ad4 = (const float*)d_in[13];
    const float* b4 = (const float*)d_in[14];
    const float* Wf1 = (const float*)d_in[15]; const float* bf1 = (const float*)d_in[16];
    const float* Wf2 = (const float*)d_in[17]; const float* bf2 = (const float*)d_in[18];
    float* out = (float*)d_out;

    const int* srcE = ei;
    const int* dstE = ei + NE;

    char* base = (char*)d_ws; size_t off = 0;
    auto alloc = [&](size_t bytes)->void*{
        void* p = base + off;
        off += (bytes + 255) & ~(size_t)255;
        return p;
    };
    int*   degi    = (int*)  alloc((size_t)NN*4);
    int*   cursor  = (int*)  alloc((size_t)NN*4);
    float* dinv    = (float*)alloc((size_t)NN*4);
    int*   rowptr  = (int*)  alloc((size_t)(NN+1)*4);
    int*   csr_src = (int*)  alloc((size_t)NE*4);
    float* h_buf   = (float*)alloc((size_t)NN*128*4);   // fp32 h for GCN layers
    u16*   hb_buf  = (u16*)  alloc((size_t)NN*256*2);   // bf16 h for GAT layers
    float* xj      = (float*)alloc((size_t)NN*432*4);   // jump concat [x1|x2|x3|x4]
    float* a_src   = (float*)alloc((size_t)NN*8*4);
    float* a_dst   = (float*)alloc((size_t)NN*8*4);
    int*   gstart  = (int*)  alloc((size_t)(NG+1)*4);
    float* pool    = (float*)alloc((size_t)NG*432*4);
    float* hfc     = (float*)alloc((size_t)NG*128*4);

    hipMemsetAsync(degi, 0, (size_t)NN*4, stream);
    hipMemsetAsync(cursor, 0, (size_t)NN*4, stream);
    hipMemsetAsync(pool, 0, (size_t)NG*432*4, stream);

    const int EB = (NE + 255)/256;
    const int NB = (NN + 255)/256;

    k_count  <<<EB, 256, 0, stream>>>(dstE, degi, NE);
    k_dinv   <<<NB, 256, 0, stream>>>(degi, dinv, NN);
    k_scan   <<<1, 1024, 0, stream>>>(degi, rowptr, NN);
    k_scatter<<<EB, 256, 0, stream>>>(srcE, dstE, rowptr, cursor, csr_src, NE);

    // GCN layer 1: x[N,128] @ W1[128,16] -> agg -> relu -> xj[:,0:16]
    k_mm<128,16> <<<(NN+15)/16, 256, 0, stream>>>(x, 128, W1, h_buf, NN);
    k_gcn_agg<16><<<(NN+15)/16, 256, 0, stream>>>(h_buf, dinv, rowptr, csr_src, b1, xj + 0, 432, NN);

    // GCN layer 2: x1[N,16] @ W2[16,32] -> agg -> relu -> xj[:,16:48]
    k_mm<16,32>  <<<(NN+7)/8, 256, 0, stream>>>(xj + 0, 432, W2, h_buf, NN);
    k_gcn_agg<32><<<(NN+7)/8, 256, 0, stream>>>(h_buf, dinv, rowptr, csr_src, b2, xj + 16, 432, NN);

    // GAT layer 3: x2[N,32] @ W3[32,128] (4 heads x 32), bf16 h
    k_mm_bf<32,128><<<(NN+1)/2, 256, 0, stream>>>(xj + 16, 432, W3, hb_buf, NN);
    k_att<4,32>  <<<(NN*4 + 255)/256, 256, 0, stream>>>(hb_buf, as3, ad3, a_src, a_dst, NN);
    k_gat_agg<4,32><<<(NN+3)/4, 256, 0, stream>>>(hb_buf, a_src, a_dst, rowptr, csr_src, b3, xj + 48, 432, NN);

    // GAT layer 4: x3[N,128] @ W4[128,256] (8 heads x 32), bf16 h
    {
        dim3 grid(4, (NN + 63)/64);
        k_mm4<<<grid, 256, 0, stream>>>(xj + 48, 432, W4, hb_buf, NN);
    }
    k_att<8,32>  <<<(NN*8 + 255)/256, 256, 0, stream>>>(hb_buf, as4, ad4, a_src, a_dst, NN);
    k_gat_agg<8,32><<<(NN+3)/4, 256, 0, stream>>>(hb_buf, a_src, a_dst, rowptr, csr_src, b4, xj + 176, 432, NN);

    // pooling + FC
    k_bounds<<<1, 256, 0, stream>>>(batch, gstart, NN, NG);
    k_pool_sum<<<(NN+31)/32, 256, 0, stream>>>(xj, batch, pool);
    k_fc1   <<<NG, 128, 0, stream>>>(pool, gstart, Wf1, bf1, hfc);
    k_fc2   <<<NG, 128, 0, stream>>>(hfc, Wf2, bf2, out);
}

// Round 4
// 608.561 us; speedup vs baseline: 1.5713x; 1.1947x over previous
//
#include <hip/hip_runtime.h>
#include <hip/hip_bf16.h>

#define NN 50000
#define NE 800000
#define NG 128

typedef unsigned short u16;

__device__ __forceinline__ float lrelu(float x){ return x > 0.f ? x : 0.2f*x; }
__device__ __forceinline__ float bf2f(u16 u){ return __uint_as_float(((unsigned int)u) << 16); }
__device__ __forceinline__ u16 f2bf(float f){
    __hip_bfloat16 h = __float2bfloat16(f);
    return *(u16*)&h;
}
// unpack 8 bf16 (as uint4) -> 8 floats; element 2k = low half, 2k+1 = high half
__device__ __forceinline__ void unpack8(uint4 t, float* f){
    f[0]=__uint_as_float(t.x<<16); f[1]=__uint_as_float(t.x&0xffff0000u);
    f[2]=__uint_as_float(t.y<<16); f[3]=__uint_as_float(t.y&0xffff0000u);
    f[4]=__uint_as_float(t.z<<16); f[5]=__uint_as_float(t.z&0xffff0000u);
    f[6]=__uint_as_float(t.w<<16); f[7]=__uint_as_float(t.w&0xffff0000u);
}

// ---------------- CSR build ----------------
__global__ void k_count(const int* __restrict__ dst, int* __restrict__ degi, int E){
    int e = blockIdx.x*blockDim.x + threadIdx.x;
    if (e < E) atomicAdd(&degi[dst[e]], 1);
}

__global__ void k_dinv(const int* __restrict__ degi, float* __restrict__ dinv, int n){
    int i = blockIdx.x*blockDim.x + threadIdx.x;
    if (i < n) dinv[i] = rsqrtf((float)(degi[i] + 1));   // +1 = self loop
}

// single-block exclusive scan over n ints, 1024 threads
__global__ void k_scan(const int* __restrict__ deg, int* __restrict__ rowptr, int n){
    const int T = 1024;
    __shared__ int lds[T];
    int per = (n + T - 1) / T;
    int start = threadIdx.x * per;
    int end   = min(start + per, n);
    int s = 0;
    for (int i = start; i < end; i++) s += deg[i];
    lds[threadIdx.x] = s;
    __syncthreads();
    for (int off = 1; off < T; off <<= 1){
        int t = (threadIdx.x >= off) ? lds[threadIdx.x - off] : 0;
        __syncthreads();
        lds[threadIdx.x] += t;
        __syncthreads();
    }
    int run = lds[threadIdx.x] - s;
    for (int i = start; i < end; i++){ rowptr[i] = run; run += deg[i]; }
    if (threadIdx.x == T-1) rowptr[n] = run;
}

__global__ void k_scatter(const int* __restrict__ src, const int* __restrict__ dst,
                          const int* __restrict__ rowptr, int* __restrict__ cursor,
                          int* __restrict__ csr_src, int E){
    int e = blockIdx.x*blockDim.x + threadIdx.x;
    if (e < E){
        int d = dst[e];
        int pos = rowptr[d] + atomicAdd(&cursor[d], 1);
        csr_src[pos] = src[e];
    }
}

// ---------------- small matmul (fp32 out) ----------------
template<int K, int M>
__global__ void k_mm(const float* __restrict__ in, int istride,
                     const float* __restrict__ W, float* __restrict__ out, int n){
    __shared__ float wl[K*M];
    for (int i = threadIdx.x; i < K*M; i += blockDim.x) wl[i] = W[i];
    __syncthreads();
    constexpr int NPB = 256 / M;
    int m  = threadIdx.x % M;
    int nl = threadIdx.x / M;
    int node = blockIdx.x * NPB + nl;
    if (node >= n) return;
    const float* row = in + (size_t)node * istride;
    float acc = 0.f;
#pragma unroll 8
    for (int k = 0; k < K; k++) acc += row[k] * wl[k*M + m];
    out[(size_t)node*M + m] = acc;
}

// bf16-out variant
template<int K, int M>
__global__ void k_mm_bf(const float* __restrict__ in, int istride,
                        const float* __restrict__ W, u16* __restrict__ out, int n){
    __shared__ float wl[K*M];
    for (int i = threadIdx.x; i < K*M; i += blockDim.x) wl[i] = W[i];
    __syncthreads();
    constexpr int NPB = 256 / M;
    int m  = threadIdx.x % M;
    int nl = threadIdx.x / M;
    int node = blockIdx.x * NPB + nl;
    if (node >= n) return;
    const float* row = in + (size_t)node * istride;
    float acc = 0.f;
#pragma unroll 8
    for (int k = 0; k < K; k++) acc += row[k] * wl[k*M + m];
    out[(size_t)node*M + m] = f2bf(acc);
}

// ---------------- mm4: [N,128] @ [128,256] -> bf16, 64x64 tiles ----------------
__global__ void k_mm4(const float* __restrict__ in, int istride,
                      const float* __restrict__ W, u16* __restrict__ out, int n){
    __shared__ __align__(16) float xs[64][68];
    __shared__ __align__(16) float ws[64][68];
    int tid = threadIdx.x;
    int tx = tid & 15;
    int ty = tid >> 4;
    int nbase = blockIdx.y * 64;
    int cbase = blockIdx.x * 64;
    float acc[4][4] = {};
    for (int kb = 0; kb < 128; kb += 64){
#pragma unroll
        for (int p = 0; p < 4; p++){
            int r = p*16 + ty;
            int nn = nbase + r;
            float4 v = make_float4(0.f,0.f,0.f,0.f);
            if (nn < n) v = *(const float4*)(in + (size_t)nn*istride + kb + tx*4);
            *(float4*)&xs[r][tx*4] = v;
            float4 wv = *(const float4*)(W + (size_t)(kb + r)*256 + cbase + tx*4);
            *(float4*)&ws[r][tx*4] = wv;
        }
        __syncthreads();
#pragma unroll 16
        for (int k = 0; k < 64; k++){
            float4 wv = *(const float4*)&ws[k][tx*4];
#pragma unroll
            for (int i2 = 0; i2 < 4; i2++){
                float a = xs[ty*4 + i2][k];
                acc[i2][0] += a*wv.x; acc[i2][1] += a*wv.y;
                acc[i2][2] += a*wv.z; acc[i2][3] += a*wv.w;
            }
        }
        __syncthreads();
    }
#pragma unroll
    for (int i2 = 0; i2 < 4; i2++){
        int nn = nbase + ty*4 + i2;
        if (nn < n){
            ushort4 v;
            v.x = f2bf(acc[i2][0]); v.y = f2bf(acc[i2][1]);
            v.z = f2bf(acc[i2][2]); v.w = f2bf(acc[i2][3]);
            *(ushort4*)(out + (size_t)nn*256 + cbase + tx*4) = v;
        }
    }
}

// ---------------- GCN aggregation: 16 lanes/node = S edge-slots x (C/4) chan-lanes ----------------
template<int C>
__global__ void k_gcn_agg(const float* __restrict__ h, const float* __restrict__ dinv,
                          const int* __restrict__ rowptr, const int* __restrict__ csr_src,
                          const float* __restrict__ b, float* __restrict__ out,
                          int ostride, int n){
    constexpr int CL = C/4;          // lanes covering channels (4 or 8)
    constexpr int S  = 16/CL;        // edge slots (4 or 2)
    int lin = threadIdx.x & 15;
    int i = blockIdx.x*16 + (threadIdx.x >> 4);
    if (i >= n) return;
    int ll = lin % CL, slot = lin / CL;
    float di = dinv[i];
    float acc[4] = {0.f,0.f,0.f,0.f};
    if (slot == 0){
        float4 t = ((const float4*)(h + (size_t)i*C))[ll];
        acc[0]=di*t.x; acc[1]=di*t.y; acc[2]=di*t.z; acc[3]=di*t.w;
    }
    int e0 = rowptr[i], e1 = rowptr[i+1];
    for (int e = e0 + slot; e < e1; e += S){
        int j = csr_src[e];
        float dj = dinv[j];
        float4 t = ((const float4*)(h + (size_t)j*C))[ll];
        acc[0]+=dj*t.x; acc[1]+=dj*t.y; acc[2]+=dj*t.z; acc[3]+=dj*t.w;
    }
#pragma unroll
    for (int m = CL; m < 16; m <<= 1){
#pragma unroll
        for (int k=0;k<4;k++) acc[k] += __shfl_xor(acc[k], m, 64);
    }
    if (slot == 0){
        float4 o;
        o.x = fmaxf(di*acc[0] + b[ll*4+0], 0.f);
        o.y = fmaxf(di*acc[1] + b[ll*4+1], 0.f);
        o.z = fmaxf(di*acc[2] + b[ll*4+2], 0.f);
        o.w = fmaxf(di*acc[3] + b[ll*4+3], 0.f);
        *(float4*)(out + (size_t)i*ostride + ll*4) = o;
    }
}

// ---------------- GAT attention coefficients (bf16 h, uint4 loads) ----------------
template<int H, int C>
__global__ void k_att(const u16* __restrict__ h, const float* __restrict__ att_s,
                      const float* __restrict__ att_d, float* __restrict__ asrc,
                      float* __restrict__ adst, int n){
    __shared__ float ss[H*C], sd[H*C];
    for (int k = threadIdx.x; k < H*C; k += 256){ ss[k]=att_s[k]; sd[k]=att_d[k]; }
    __syncthreads();
    int idx = blockIdx.x*256 + threadIdx.x;
    int i = idx / H, hh = idx % H;
    if (i >= n) return;
    const uint4* rp = (const uint4*)(h + (size_t)i*H*C + hh*C);
    float s=0.f, d=0.f;
#pragma unroll
    for (int q = 0; q < C/8; q++){
        float f[8]; unpack8(rp[q], f);
#pragma unroll
        for (int k=0;k<8;k++){ s += f[k]*ss[hh*C+q*8+k]; d += f[k]*sd[hh*C+q*8+k]; }
    }
    asrc[idx]=s; adst[idx]=d;
}

// ---------------- GAT aggregation: wave/node, S edge-slots x CL chan-lanes, 16B loads ----------------
template<int H, int C>
__global__ void k_gat_agg(const u16* __restrict__ h, const float* __restrict__ asrc,
                          const float* __restrict__ adst, const int* __restrict__ rowptr,
                          const int* __restrict__ csr_src, const float* __restrict__ b,
                          float* __restrict__ out, int ostride, int n){
    constexpr int HC = H*C;          // 256 or 128
    constexpr int CL = HC/8;         // chan-lanes (32 or 16), 8 bf16 each
    constexpr int S  = 64/CL;        // edge slots (2 or 4)
    int lane = threadIdx.x & 63;
    int wid  = threadIdx.x >> 6;
    int i = blockIdx.x*4 + wid;
    if (i >= n) return;
    int ll   = lane % CL;
    int slot = lane / CL;
    int head = (ll*8)/C;
    float ad = adst[(size_t)i*H + head];
    float acc[8] = {0.f,0.f,0.f,0.f,0.f,0.f,0.f,0.f};
    float s = 0.f;
    if (slot == 0){
        float wself = expf(lrelu(asrc[(size_t)i*H + head] + ad));
        uint4 t = ((const uint4*)(h + (size_t)i*HC))[ll];
        float f[8]; unpack8(t, f);
#pragma unroll
        for (int k=0;k<8;k++) acc[k] = wself*f[k];
        s = wself;
    }
    int e0 = rowptr[i], e1 = rowptr[i+1];
    for (int e = e0 + slot; e < e1; e += S){
        int j = csr_src[e];
        float w = expf(lrelu(asrc[(size_t)j*H + head] + ad));
        uint4 t = ((const uint4*)(h + (size_t)j*HC))[ll];
        float f[8]; unpack8(t, f);
#pragma unroll
        for (int k=0;k<8;k++) acc[k] += w*f[k];
        s += w;
    }
#pragma unroll
    for (int m = CL; m < 64; m <<= 1){
        s += __shfl_xor(s, m, 64);
#pragma unroll
        for (int k=0;k<8;k++) acc[k] += __shfl_xor(acc[k], m, 64);
    }
    if (slot == 0){
        float inv = 1.f / s;
        float o[8];
#pragma unroll
        for (int k=0;k<8;k++) o[k] = fmaxf(acc[k]*inv + b[ll*8+k], 0.f);
        float4* dst0 = (float4*)(out + (size_t)i*ostride + ll*8);
        dst0[0] = make_float4(o[0],o[1],o[2],o[3]);
        dst0[1] = make_float4(o[4],o[5],o[6],o[7]);
    }
}

// ---------------- pooling + FC ----------------
__global__ void k_bounds(const int* __restrict__ batch, int* __restrict__ gstart, int n, int G){
    int g = threadIdx.x;
    if (g > G) return;
    int lo = 0, hi = n;
    while (lo < hi){ int mid = (lo+hi) >> 1; if (batch[mid] < g) lo = mid+1; else hi = mid; }
    gstart[g] = lo;
}

__global__ void k_pool_sum(const float* __restrict__ xj, const int* __restrict__ batch,
                           float* __restrict__ pool){
    int nb = blockIdx.x * 32;
    int ne = min(nb + 32, NN);
    if (nb >= NN) return;
    int c0 = threadIdx.x;
    int c1 = threadIdx.x + 256;
    float a0 = 0.f, a1 = 0.f;
    int curg = batch[nb];
    for (int nn = nb; nn < ne; nn++){
        int g = batch[nn];
        if (g != curg){
            atomicAdd(&pool[curg*432 + c0], a0);
            if (c1 < 432) atomicAdd(&pool[curg*432 + c1], a1);
            a0 = 0.f; a1 = 0.f; curg = g;
        }
        a0 += xj[(size_t)nn*432 + c0];
        if (c1 < 432) a1 += xj[(size_t)nn*432 + c1];
    }
    atomicAdd(&pool[curg*432 + c0], a0);
    if (c1 < 432) atomicAdd(&pool[curg*432 + c1], a1);
}

__global__ void k_fc1(const float* __restrict__ pool, const int* __restrict__ gstart,
                      const float* __restrict__ W, const float* __restrict__ b,
                      float* __restrict__ hfc){
    int g = blockIdx.x, j = threadIdx.x;
    int cnt = gstart[g+1] - gstart[g];
    float invc = 1.f / (float)max(cnt, 1);
    float acc = 0.f;
    for (int k = 0; k < 432; k++) acc += pool[g*432 + k] * W[k*128 + j];
    hfc[g*128 + j] = fmaxf(acc * invc + b[j], 0.f);
}

__global__ void k_fc2(const float* __restrict__ hfc, const float* __restrict__ W,
                      const float* __restrict__ b, float* __restrict__ out){
    int g = blockIdx.x, t = threadIdx.x;
    float p = hfc[g*128 + t] * W[t];
    for (int off = 32; off > 0; off >>= 1) p += __shfl_down(p, off, 64);
    __shared__ float part[2];
    if ((t & 63) == 0) part[t >> 6] = p;
    __syncthreads();
    if (t == 0) out[g] = part[0] + part[1] + b[0];
}

extern "C" void kernel_launch(void* const* d_in, const int* in_sizes, int n_in,
                              void* d_out, int out_size, void* d_ws, size_t ws_size,
                              hipStream_t stream){
    const float* x     = (const float*)d_in[0];
    const int*   ei    = (const int*)  d_in[1];
    const int*   batch = (const int*)  d_in[2];
    const float* W1 = (const float*)d_in[3];  const float* b1 = (const float*)d_in[4];
    const float* W2 = (const float*)d_in[5];  const float* b2 = (const float*)d_in[6];
    const float* W3 = (const float*)d_in[7];
    const float* as3 = (const float*)d_in[8]; const float* ad3 = (const float*)d_in[9];
    const float* b3 = (const float*)d_in[10];
    const float* W4 = (const float*)d_in[11];
    const float* as4 = (const float*)d_in[12]; const float* ad4 = (const float*)d_in[13];
    const float* b4 = (const float*)d_in[14];
    const float* Wf1 = (const float*)d_in[15]; const float* bf1 = (const float*)d_in[16];
    const float* Wf2 = (const float*)d_in[17]; const float* bf2 = (const float*)d_in[18];
    float* out = (float*)d_out;

    const int* srcE = ei;
    const int* dstE = ei + NE;

    char* base = (char*)d_ws; size_t off = 0;
    auto alloc = [&](size_t bytes)->void*{
        void* p = base + off;
        off += (bytes + 255) & ~(size_t)255;
        return p;
    };
    int*   degi    = (int*)  alloc((size_t)NN*4);
    int*   cursor  = (int*)  alloc((size_t)NN*4);
    float* dinv    = (float*)alloc((size_t)NN*4);
    int*   rowptr  = (int*)  alloc((size_t)(NN+1)*4);
    int*   csr_src = (int*)  alloc((size_t)NE*4);
    float* h_buf   = (float*)alloc((size_t)NN*128*4);   // fp32 h for GCN layers
    u16*   hb_buf  = (u16*)  alloc((size_t)NN*256*2);   // bf16 h for GAT layers
    float* xj      = (float*)alloc((size_t)NN*432*4);   // jump concat [x1|x2|x3|x4]
    float* a_src   = (float*)alloc((size_t)NN*8*4);
    float* a_dst   = (float*)alloc((size_t)NN*8*4);
    int*   gstart  = (int*)  alloc((size_t)(NG+1)*4);
    float* pool    = (float*)alloc((size_t)NG*432*4);
    float* hfc     = (float*)alloc((size_t)NG*128*4);

    hipMemsetAsync(degi, 0, (size_t)NN*4, stream);
    hipMemsetAsync(cursor, 0, (size_t)NN*4, stream);
    hipMemsetAsync(pool, 0, (size_t)NG*432*4, stream);

    const int EB = (NE + 255)/256;
    const int NB = (NN + 255)/256;

    k_count  <<<EB, 256, 0, stream>>>(dstE, degi, NE);
    k_dinv   <<<NB, 256, 0, stream>>>(degi, dinv, NN);
    k_scan   <<<1, 1024, 0, stream>>>(degi, rowptr, NN);
    k_scatter<<<EB, 256, 0, stream>>>(srcE, dstE, rowptr, cursor, csr_src, NE);

    // GCN layer 1: x[N,128] @ W1[128,16] -> agg -> relu -> xj[:,0:16]
    k_mm<128,16> <<<(NN+15)/16, 256, 0, stream>>>(x, 128, W1, h_buf, NN);
    k_gcn_agg<16><<<(NN+15)/16, 256, 0, stream>>>(h_buf, dinv, rowptr, csr_src, b1, xj + 0, 432, NN);

    // GCN layer 2: x1[N,16] @ W2[16,32] -> agg -> relu -> xj[:,16:48]
    k_mm<16,32>  <<<(NN+7)/8, 256, 0, stream>>>(xj + 0, 432, W2, h_buf, NN);
    k_gcn_agg<32><<<(NN+15)/16, 256, 0, stream>>>(h_buf, dinv, rowptr, csr_src, b2, xj + 16, 432, NN);

    // GAT layer 3: x2[N,32] @ W3[32,128] (4 heads x 32), bf16 h
    k_mm_bf<32,128><<<(NN+1)/2, 256, 0, stream>>>(xj + 16, 432, W3, hb_buf, NN);
    k_att<4,32>  <<<(NN*4 + 255)/256, 256, 0, stream>>>(hb_buf, as3, ad3, a_src, a_dst, NN);
    k_gat_agg<4,32><<<(NN+3)/4, 256, 0, stream>>>(hb_buf, a_src, a_dst, rowptr, csr_src, b3, xj + 48, 432, NN);

    // GAT layer 4: x3[N,128] @ W4[128,256] (8 heads x 32), bf16 h
    {
        dim3 grid(4, (NN + 63)/64);
        k_mm4<<<grid, 256, 0, stream>>>(xj + 48, 432, W4, hb_buf, NN);
    }
    k_att<8,32>  <<<(NN*8 + 255)/256, 256, 0, stream>>>(hb_buf, as4, ad4, a_src, a_dst, NN);
    k_gat_agg<8,32><<<(NN+3)/4, 256, 0, stream>>>(hb_buf, a_src, a_dst, rowptr, csr_src, b4, xj + 176, 432, NN);

    // pooling + FC
    k_bounds<<<1, 256, 0, stream>>>(batch, gstart, NN, NG);
    k_pool_sum<<<(NN+31)/32, 256, 0, stream>>>(xj, batch, pool);
    k_fc1   <<<NG, 128, 0, stream>>>(pool, gstart, Wf1, bf1, hfc);
    k_fc2   <<<NG, 128, 0, stream>>>(hfc, Wf2, bf2, out);
}

// Round 5
// 515.903 us; speedup vs baseline: 1.8535x; 1.1796x over previous
//
#include <hip/hip_runtime.h>
#include <hip/hip_bf16.h>

#define NN 50000
#define NE 800000
#define NG 128

typedef unsigned short u16;

__device__ __forceinline__ float lrelu(float x){ return x > 0.f ? x : 0.2f*x; }
__device__ __forceinline__ float bf2f(u16 u){ return __uint_as_float(((unsigned int)u) << 16); }
__device__ __forceinline__ u16 f2bf(float f){
    __hip_bfloat16 h = __float2bfloat16(f);
    return *(u16*)&h;
}
// unpack 8 bf16 (as uint4) -> 8 floats
__device__ __forceinline__ void unpack8(uint4 t, float* f){
    f[0]=__uint_as_float(t.x<<16); f[1]=__uint_as_float(t.x&0xffff0000u);
    f[2]=__uint_as_float(t.y<<16); f[3]=__uint_as_float(t.y&0xffff0000u);
    f[4]=__uint_as_float(t.z<<16); f[5]=__uint_as_float(t.z&0xffff0000u);
    f[6]=__uint_as_float(t.w<<16); f[7]=__uint_as_float(t.w&0xffff0000u);
}

// ---------------- CSR build ----------------
__global__ void k_count(const int* __restrict__ dst, int* __restrict__ degi, int E){
    int e = blockIdx.x*blockDim.x + threadIdx.x;
    if (e < E) atomicAdd(&degi[dst[e]], 1);
}

__global__ void k_dinv(const int* __restrict__ degi, float* __restrict__ dinv, int n){
    int i = blockIdx.x*blockDim.x + threadIdx.x;
    if (i < n) dinv[i] = rsqrtf((float)(degi[i] + 1));   // +1 = self loop
}

// hierarchical scan: stage A — per-block local exclusive scan (1024 elems/block)
__global__ void k_scan_a(const int* __restrict__ deg, int* __restrict__ rowptr,
                         int* __restrict__ bsum, int n){
    __shared__ int lds[256];
    int base = blockIdx.x*1024 + threadIdx.x*4;
    int v[4]; int s = 0;
#pragma unroll
    for (int k=0;k<4;k++){ v[k] = (base+k < n) ? deg[base+k] : 0; s += v[k]; }
    lds[threadIdx.x] = s;
    __syncthreads();
    for (int off=1; off<256; off<<=1){
        int t = (threadIdx.x>=off) ? lds[threadIdx.x-off] : 0;
        __syncthreads(); lds[threadIdx.x] += t; __syncthreads();
    }
    int run = lds[threadIdx.x] - s;   // exclusive within block
#pragma unroll
    for (int k=0;k<4;k++){ if (base+k < n) rowptr[base+k] = run; run += v[k]; }
    if (threadIdx.x == 255) bsum[blockIdx.x] = lds[255];
}

// stage B — scan the block sums (nb <= 64), write total to rowptr[n]
__global__ void k_scan_b(int* __restrict__ bsum, int* __restrict__ rowptr, int nb, int n){
    __shared__ int lds[64];
    int s = (threadIdx.x < nb) ? bsum[threadIdx.x] : 0;
    lds[threadIdx.x] = s;
    __syncthreads();
    for (int off=1; off<64; off<<=1){
        int t = (threadIdx.x>=off) ? lds[threadIdx.x-off] : 0;
        __syncthreads(); lds[threadIdx.x] += t; __syncthreads();
    }
    if (threadIdx.x < nb) bsum[threadIdx.x] = lds[threadIdx.x] - s;  // exclusive offset
    if (threadIdx.x == 63) rowptr[n] = lds[63];
}

// stage C — add block offsets
__global__ void k_scan_c(int* __restrict__ rowptr, const int* __restrict__ bsum, int n){
    int i = blockIdx.x*256 + threadIdx.x;
    int idx = i*4;
    int o = bsum[blockIdx.x];   // 1024 elems per block => same offset block-wide
#pragma unroll
    for (int k=0;k<4;k++) if (idx+k < n) rowptr[idx+k] += o;
}

__global__ void k_scatter(const int* __restrict__ src, const int* __restrict__ dst,
                          const int* __restrict__ rowptr, int* __restrict__ cursor,
                          int* __restrict__ csr_src, int E){
    int e = blockIdx.x*blockDim.x + threadIdx.x;
    if (e < E){
        int d = dst[e];
        int pos = rowptr[d] + atomicAdd(&cursor[d], 1);
        csr_src[pos] = src[e];
    }
}

// ---------------- small matmul (fp32 out) ----------------
template<int K, int M>
__global__ void k_mm(const float* __restrict__ in, int istride,
                     const float* __restrict__ W, float* __restrict__ out, int n){
    __shared__ float wl[K*M];
    for (int i = threadIdx.x; i < K*M; i += blockDim.x) wl[i] = W[i];
    __syncthreads();
    constexpr int NPB = 256 / M;
    int m  = threadIdx.x % M;
    int nl = threadIdx.x / M;
    int node = blockIdx.x * NPB + nl;
    if (node >= n) return;
    const float* row = in + (size_t)node * istride;
    float acc = 0.f;
#pragma unroll 8
    for (int k = 0; k < K; k++) acc += row[k] * wl[k*M + m];
    out[(size_t)node*M + m] = acc;
}

// bf16-out variant
template<int K, int M>
__global__ void k_mm_bf(const float* __restrict__ in, int istride,
                        const float* __restrict__ W, u16* __restrict__ out, int n){
    __shared__ float wl[K*M];
    for (int i = threadIdx.x; i < K*M; i += blockDim.x) wl[i] = W[i];
    __syncthreads();
    constexpr int NPB = 256 / M;
    int m  = threadIdx.x % M;
    int nl = threadIdx.x / M;
    int node = blockIdx.x * NPB + nl;
    if (node >= n) return;
    const float* row = in + (size_t)node * istride;
    float acc = 0.f;
#pragma unroll 8
    for (int k = 0; k < K; k++) acc += row[k] * wl[k*M + m];
    out[(size_t)node*M + m] = f2bf(acc);
}

// ---------------- mm4: [N,128] @ [128,256] -> bf16, 64x64 tiles ----------------
__global__ void k_mm4(const float* __restrict__ in, int istride,
                      const float* __restrict__ W, u16* __restrict__ out, int n){
    __shared__ __align__(16) float xs[64][68];
    __shared__ __align__(16) float ws[64][68];
    int tid = threadIdx.x;
    int tx = tid & 15;
    int ty = tid >> 4;
    int nbase = blockIdx.y * 64;
    int cbase = blockIdx.x * 64;
    float acc[4][4] = {};
    for (int kb = 0; kb < 128; kb += 64){
#pragma unroll
        for (int p = 0; p < 4; p++){
            int r = p*16 + ty;
            int nn = nbase + r;
            float4 v = make_float4(0.f,0.f,0.f,0.f);
            if (nn < n) v = *(const float4*)(in + (size_t)nn*istride + kb + tx*4);
            *(float4*)&xs[r][tx*4] = v;
            float4 wv = *(const float4*)(W + (size_t)(kb + r)*256 + cbase + tx*4);
            *(float4*)&ws[r][tx*4] = wv;
        }
        __syncthreads();
#pragma unroll 16
        for (int k = 0; k < 64; k++){
            float4 wv = *(const float4*)&ws[k][tx*4];
#pragma unroll
            for (int i2 = 0; i2 < 4; i2++){
                float a = xs[ty*4 + i2][k];
                acc[i2][0] += a*wv.x; acc[i2][1] += a*wv.y;
                acc[i2][2] += a*wv.z; acc[i2][3] += a*wv.w;
            }
        }
        __syncthreads();
    }
#pragma unroll
    for (int i2 = 0; i2 < 4; i2++){
        int nn = nbase + ty*4 + i2;
        if (nn < n){
            ushort4 v;
            v.x = f2bf(acc[i2][0]); v.y = f2bf(acc[i2][1]);
            v.z = f2bf(acc[i2][2]); v.w = f2bf(acc[i2][3]);
            *(ushort4*)(out + (size_t)nn*256 + cbase + tx*4) = v;
        }
    }
}

// ---------------- GCN aggregation: 16 lanes/node, edge loop unrolled x2 ----------------
template<int C>
__global__ void k_gcn_agg(const float* __restrict__ h, const float* __restrict__ dinv,
                          const int* __restrict__ rowptr, const int* __restrict__ csr_src,
                          const float* __restrict__ b, float* __restrict__ out,
                          int ostride, int n){
    constexpr int CL = C/4;          // chan-lanes (4 or 8)
    constexpr int S  = 16/CL;        // edge slots (4 or 2)
    int lin = threadIdx.x & 15;
    int i = blockIdx.x*16 + (threadIdx.x >> 4);
    if (i >= n) return;
    int ll = lin % CL, slot = lin / CL;
    float di = dinv[i];
    float acc[4] = {0.f,0.f,0.f,0.f};
    if (slot == 0){
        float4 t = ((const float4*)(h + (size_t)i*C))[ll];
        acc[0]=di*t.x; acc[1]=di*t.y; acc[2]=di*t.z; acc[3]=di*t.w;
    }
    int e0 = rowptr[i], e1 = rowptr[i+1];
    int e = e0 + slot;
    for (; e + S < e1; e += 2*S){
        int j0 = csr_src[e], j1 = csr_src[e+S];
        float dj0 = dinv[j0], dj1 = dinv[j1];
        float4 t0 = ((const float4*)(h + (size_t)j0*C))[ll];
        float4 t1 = ((const float4*)(h + (size_t)j1*C))[ll];
        acc[0]+=dj0*t0.x+dj1*t1.x; acc[1]+=dj0*t0.y+dj1*t1.y;
        acc[2]+=dj0*t0.z+dj1*t1.z; acc[3]+=dj0*t0.w+dj1*t1.w;
    }
    if (e < e1){
        int j = csr_src[e];
        float dj = dinv[j];
        float4 t = ((const float4*)(h + (size_t)j*C))[ll];
        acc[0]+=dj*t.x; acc[1]+=dj*t.y; acc[2]+=dj*t.z; acc[3]+=dj*t.w;
    }
#pragma unroll
    for (int m = CL; m < 16; m <<= 1){
#pragma unroll
        for (int k=0;k<4;k++) acc[k] += __shfl_xor(acc[k], m, 64);
    }
    if (slot == 0){
        float4 o;
        o.x = fmaxf(di*acc[0] + b[ll*4+0], 0.f);
        o.y = fmaxf(di*acc[1] + b[ll*4+1], 0.f);
        o.z = fmaxf(di*acc[2] + b[ll*4+2], 0.f);
        o.w = fmaxf(di*acc[3] + b[ll*4+3], 0.f);
        *(float4*)(out + (size_t)i*ostride + ll*4) = o;
    }
}

// ---------------- GAT attention coefficients (bf16 h, uint4 loads) ----------------
template<int H, int C>
__global__ void k_att(const u16* __restrict__ h, const float* __restrict__ att_s,
                      const float* __restrict__ att_d, float* __restrict__ asrc,
                      float* __restrict__ adst, int n){
    __shared__ float ss[H*C], sd[H*C];
    for (int k = threadIdx.x; k < H*C; k += 256){ ss[k]=att_s[k]; sd[k]=att_d[k]; }
    __syncthreads();
    int idx = blockIdx.x*256 + threadIdx.x;
    int i = idx / H, hh = idx % H;
    if (i >= n) return;
    const uint4* rp = (const uint4*)(h + (size_t)i*H*C + hh*C);
    float s=0.f, d=0.f;
#pragma unroll
    for (int q = 0; q < C/8; q++){
        float f[8]; unpack8(rp[q], f);
#pragma unroll
        for (int k=0;k<8;k++){ s += f[k]*ss[hh*C+q*8+k]; d += f[k]*sd[hh*C+q*8+k]; }
    }
    asrc[idx]=s; adst[idx]=d;
}

// ---------------- GAT aggregation: wave/node, edge loop unrolled x2 ----------------
template<int H, int C>
__global__ void k_gat_agg(const u16* __restrict__ h, const float* __restrict__ asrc,
                          const float* __restrict__ adst, const int* __restrict__ rowptr,
                          const int* __restrict__ csr_src, const float* __restrict__ b,
                          float* __restrict__ out, int ostride, int n){
    constexpr int HC = H*C;          // 256 or 128
    constexpr int CL = HC/8;         // chan-lanes (32 or 16), 8 bf16 each
    constexpr int S  = 64/CL;        // edge slots (2 or 4)
    int lane = threadIdx.x & 63;
    int wid  = threadIdx.x >> 6;
    int i = blockIdx.x*4 + wid;
    if (i >= n) return;
    int ll   = lane % CL;
    int slot = lane / CL;
    int head = (ll*8)/C;
    float ad = adst[(size_t)i*H + head];
    float acc[8] = {0.f,0.f,0.f,0.f,0.f,0.f,0.f,0.f};
    float s = 0.f;
    if (slot == 0){
        float wself = expf(lrelu(asrc[(size_t)i*H + head] + ad));
        uint4 t = ((const uint4*)(h + (size_t)i*HC))[ll];
        float f[8]; unpack8(t, f);
#pragma unroll
        for (int k=0;k<8;k++) acc[k] = wself*f[k];
        s = wself;
    }
    int e0 = rowptr[i], e1 = rowptr[i+1];
    int e = e0 + slot;
    for (; e + S < e1; e += 2*S){
        int j0 = csr_src[e], j1 = csr_src[e+S];
        float w0 = expf(lrelu(asrc[(size_t)j0*H + head] + ad));
        float w1 = expf(lrelu(asrc[(size_t)j1*H + head] + ad));
        uint4 t0 = ((const uint4*)(h + (size_t)j0*HC))[ll];
        uint4 t1 = ((const uint4*)(h + (size_t)j1*HC))[ll];
        float f0[8], f1[8]; unpack8(t0, f0); unpack8(t1, f1);
#pragma unroll
        for (int k=0;k<8;k++) acc[k] += w0*f0[k] + w1*f1[k];
        s += w0 + w1;
    }
    if (e < e1){
        int j = csr_src[e];
        float w = expf(lrelu(asrc[(size_t)j*H + head] + ad));
        uint4 t = ((const uint4*)(h + (size_t)j*HC))[ll];
        float f[8]; unpack8(t, f);
#pragma unroll
        for (int k=0;k<8;k++) acc[k] += w*f[k];
        s += w;
    }
#pragma unroll
    for (int m = CL; m < 64; m <<= 1){
        s += __shfl_xor(s, m, 64);
#pragma unroll
        for (int k=0;k<8;k++) acc[k] += __shfl_xor(acc[k], m, 64);
    }
    if (slot == 0){
        float inv = 1.f / s;
        float o[8];
#pragma unroll
        for (int k=0;k<8;k++) o[k] = fmaxf(acc[k]*inv + b[ll*8+k], 0.f);
        float4* dst0 = (float4*)(out + (size_t)i*ostride + ll*8);
        dst0[0] = make_float4(o[0],o[1],o[2],o[3]);
        dst0[1] = make_float4(o[4],o[5],o[6],o[7]);
    }
}

// ---------------- pooling + FC ----------------
__global__ void k_bounds(const int* __restrict__ batch, int* __restrict__ gstart, int n, int G){
    int g = threadIdx.x;
    if (g > G) return;
    int lo = 0, hi = n;
    while (lo < hi){ int mid = (lo+hi) >> 1; if (batch[mid] < g) lo = mid+1; else hi = mid; }
    gstart[g] = lo;
}

__global__ void k_pool_sum(const float* __restrict__ xj, const int* __restrict__ batch,
                           float* __restrict__ pool){
    int nb = blockIdx.x * 32;
    int ne = min(nb + 32, NN);
    if (nb >= NN) return;
    int c0 = threadIdx.x;
    int c1 = threadIdx.x + 256;
    float a0 = 0.f, a1 = 0.f;
    int curg = batch[nb];
    for (int nn = nb; nn < ne; nn++){
        int g = batch[nn];
        if (g != curg){
            atomicAdd(&pool[curg*432 + c0], a0);
            if (c1 < 432) atomicAdd(&pool[curg*432 + c1], a1);
            a0 = 0.f; a1 = 0.f; curg = g;
        }
        a0 += xj[(size_t)nn*432 + c0];
        if (c1 < 432) a1 += xj[(size_t)nn*432 + c1];
    }
    atomicAdd(&pool[curg*432 + c0], a0);
    if (c1 < 432) atomicAdd(&pool[curg*432 + c1], a1);
}

__global__ void k_fc1(const float* __restrict__ pool, const int* __restrict__ gstart,
                      const float* __restrict__ W, const float* __restrict__ b,
                      float* __restrict__ hfc){
    int g = blockIdx.x, j = threadIdx.x;
    int cnt = gstart[g+1] - gstart[g];
    float invc = 1.f / (float)max(cnt, 1);
    float acc = 0.f;
    for (int k = 0; k < 432; k++) acc += pool[g*432 + k] * W[k*128 + j];
    hfc[g*128 + j] = fmaxf(acc * invc + b[j], 0.f);
}

__global__ void k_fc2(const float* __restrict__ hfc, const float* __restrict__ W,
                      const float* __restrict__ b, float* __restrict__ out){
    int g = blockIdx.x, t = threadIdx.x;
    float p = hfc[g*128 + t] * W[t];
    for (int off = 32; off > 0; off >>= 1) p += __shfl_down(p, off, 64);
    __shared__ float part[2];
    if ((t & 63) == 0) part[t >> 6] = p;
    __syncthreads();
    if (t == 0) out[g] = part[0] + part[1] + b[0];
}

extern "C" void kernel_launch(void* const* d_in, const int* in_sizes, int n_in,
                              void* d_out, int out_size, void* d_ws, size_t ws_size,
                              hipStream_t stream){
    const float* x     = (const float*)d_in[0];
    const int*   ei    = (const int*)  d_in[1];
    const int*   batch = (const int*)  d_in[2];
    const float* W1 = (const float*)d_in[3];  const float* b1 = (const float*)d_in[4];
    const float* W2 = (const float*)d_in[5];  const float* b2 = (const float*)d_in[6];
    const float* W3 = (const float*)d_in[7];
    const float* as3 = (const float*)d_in[8]; const float* ad3 = (const float*)d_in[9];
    const float* b3 = (const float*)d_in[10];
    const float* W4 = (const float*)d_in[11];
    const float* as4 = (const float*)d_in[12]; const float* ad4 = (const float*)d_in[13];
    const float* b4 = (const float*)d_in[14];
    const float* Wf1 = (const float*)d_in[15]; const float* bf1 = (const float*)d_in[16];
    const float* Wf2 = (const float*)d_in[17]; const float* bf2 = (const float*)d_in[18];
    float* out = (float*)d_out;

    const int* srcE = ei;
    const int* dstE = ei + NE;

    char* base = (char*)d_ws; size_t off = 0;
    auto alloc = [&](size_t bytes)->void*{
        void* p = base + off;
        off += (bytes + 255) & ~(size_t)255;
        return p;
    };
    int*   degi    = (int*)  alloc((size_t)NN*4);
    int*   cursor  = (int*)  alloc((size_t)NN*4);
    float* dinv    = (float*)alloc((size_t)NN*4);
    int*   rowptr  = (int*)  alloc((size_t)(NN+1)*4);
    int*   bsum    = (int*)  alloc(64*4);
    int*   csr_src = (int*)  alloc((size_t)NE*4);
    float* h_buf   = (float*)alloc((size_t)NN*128*4);   // fp32 h for GCN layers
    u16*   hb_buf  = (u16*)  alloc((size_t)NN*256*2);   // bf16 h for GAT layers
    float* xj      = (float*)alloc((size_t)NN*432*4);   // jump concat [x1|x2|x3|x4]
    float* a_src   = (float*)alloc((size_t)NN*8*4);
    float* a_dst   = (float*)alloc((size_t)NN*8*4);
    int*   gstart  = (int*)  alloc((size_t)(NG+1)*4);
    float* pool    = (float*)alloc((size_t)NG*432*4);
    float* hfc     = (float*)alloc((size_t)NG*128*4);

    hipMemsetAsync(degi, 0, (size_t)NN*4, stream);
    hipMemsetAsync(cursor, 0, (size_t)NN*4, stream);
    hipMemsetAsync(pool, 0, (size_t)NG*432*4, stream);

    const int EB = (NE + 255)/256;
    const int NB = (NN + 255)/256;
    const int SB = (NN + 1023)/1024;   // 49 scan blocks

    k_count  <<<EB, 256, 0, stream>>>(dstE, degi, NE);
    k_dinv   <<<NB, 256, 0, stream>>>(degi, dinv, NN);
    k_scan_a <<<SB, 256, 0, stream>>>(degi, rowptr, bsum, NN);
    k_scan_b <<<1, 64, 0, stream>>>(bsum, rowptr, SB, NN);
    k_scan_c <<<SB, 256, 0, stream>>>(rowptr, bsum, NN);
    k_scatter<<<EB, 256, 0, stream>>>(srcE, dstE, rowptr, cursor, csr_src, NE);

    // GCN layer 1: x[N,128] @ W1[128,16] -> agg -> relu -> xj[:,0:16]
    k_mm<128,16> <<<(NN+15)/16, 256, 0, stream>>>(x, 128, W1, h_buf, NN);
    k_gcn_agg<16><<<(NN+15)/16, 256, 0, stream>>>(h_buf, dinv, rowptr, csr_src, b1, xj + 0, 432, NN);

    // GCN layer 2: x1[N,16] @ W2[16,32] -> agg -> relu -> xj[:,16:48]
    k_mm<16,32>  <<<(NN+7)/8, 256, 0, stream>>>(xj + 0, 432, W2, h_buf, NN);
    k_gcn_agg<32><<<(NN+15)/16, 256, 0, stream>>>(h_buf, dinv, rowptr, csr_src, b2, xj + 16, 432, NN);

    // GAT layer 3: x2[N,32] @ W3[32,128] (4 heads x 32), bf16 h
    k_mm_bf<32,128><<<(NN+1)/2, 256, 0, stream>>>(xj + 16, 432, W3, hb_buf, NN);
    k_att<4,32>  <<<(NN*4 + 255)/256, 256, 0, stream>>>(hb_buf, as3, ad3, a_src, a_dst, NN);
    k_gat_agg<4,32><<<(NN+3)/4, 256, 0, stream>>>(hb_buf, a_src, a_dst, rowptr, csr_src, b3, xj + 48, 432, NN);

    // GAT layer 4: x3[N,128] @ W4[128,256] (8 heads x 32), bf16 h
    {
        dim3 grid(4, (NN + 63)/64);
        k_mm4<<<grid, 256, 0, stream>>>(xj + 48, 432, W4, hb_buf, NN);
    }
    k_att<8,32>  <<<(NN*8 + 255)/256, 256, 0, stream>>>(hb_buf, as4, ad4, a_src, a_dst, NN);
    k_gat_agg<8,32><<<(NN+3)/4, 256, 0, stream>>>(hb_buf, a_src, a_dst, rowptr, csr_src, b4, xj + 176, 432, NN);

    // pooling + FC
    k_bounds<<<1, 256, 0, stream>>>(batch, gstart, NN, NG);
    k_pool_sum<<<(NN+31)/32, 256, 0, stream>>>(xj, batch, pool);
    k_fc1   <<<NG, 128, 0, stream>>>(pool, gstart, Wf1, bf1, hfc);
    k_fc2   <<<NG, 128, 0, stream>>>(hfc, Wf2, bf2, out);
}